// Round 15
// baseline (316.474 us; speedup 1.0000x reference)
//
#include <hip/hip_runtime.h>
#include <math.h>

#define NB 16
#define NS 4096
#define DIN 512
#define NG 2
#define NC 320
#define GC 640          // NG*NC
#define DG 128          // D_out / G
#define NROW (NB*NS)    // 65536
#define NKT 16          // K tiles of 32
#define NCT 40          // global col tiles of 16
#define EPSV 1e-10f

typedef __attribute__((ext_vector_type(4))) float f32x4;
typedef __attribute__((ext_vector_type(8))) _Float16 f16x8;

// async global->LDS (fallback path only)
__device__ __forceinline__ void gload_lds16(const void* g, void* l) {
    __builtin_amdgcn_global_load_lds(
        (const __attribute__((address_space(1))) void*)g,
        (__attribute__((address_space(3))) void*)l,
        16, 0, 0);
}

// ---------- W: split f32 -> (f16 hi, f16 lo*2048) packed in MFMA-frag order ----------
__global__ __launch_bounds__(256) void cvt_split_pack(
    const float* __restrict__ W, _Float16* __restrict__ hp, _Float16* __restrict__ lp)
{
    int idx = blockIdx.x * 256 + threadIdx.x;   // one per (col, k8); 640*64
    if (idx >= GC * (DIN / 8)) return;
    int col = idx >> 6, k8 = idx & 63;
    int kslice = k8 >> 2, kq = k8 & 3, ntile = col >> 4;
    int ln = (col & 15) + 16 * kq;
    size_t dst = (((size_t)kslice * NCT + ntile) * 64 + ln) * 8;
    const float* src = W + (size_t)col * DIN + k8 * 8;
    f16x8 h, l;
    #pragma unroll
    for (int j = 0; j < 8; ++j) {
        float x = src[j];
        _Float16 hh = (_Float16)x;
        h[j] = hh;
        l[j] = (_Float16)((x - (float)hh) * 2048.0f);
    }
    *(f16x8*)(hp + dst) = h;
    *(f16x8*)(lp + dst) = l;
}

// ---------- MFMA GEMM v9: r9 geometry + depth-2 A prefetch (scalar-coded, no array refs) ----------
// logits = Ah*Bh + 2^-11*(Ah*Bl + Al*Bh) + b   (bit-identical chain to r8/r9)

#define WRITE_A(buf, va, vb)                                              \
    do {                                                                  \
        float xs0=(va).x, xs1=(va).y, xs2=(va).z, xs3=(va).w;             \
        float xs4=(vb).x, xs5=(vb).y, xs6=(vb).z, xs7=(vb).w;             \
        f16x8 hh_, ll_;                                                   \
        _Float16 h0=(_Float16)xs0; hh_[0]=h0; ll_[0]=(_Float16)((xs0-(float)h0)*2048.0f); \
        _Float16 h1=(_Float16)xs1; hh_[1]=h1; ll_[1]=(_Float16)((xs1-(float)h1)*2048.0f); \
        _Float16 h2=(_Float16)xs2; hh_[2]=h2; ll_[2]=(_Float16)((xs2-(float)h2)*2048.0f); \
        _Float16 h3=(_Float16)xs3; hh_[3]=h3; ll_[3]=(_Float16)((xs3-(float)h3)*2048.0f); \
        _Float16 h4=(_Float16)xs4; hh_[4]=h4; ll_[4]=(_Float16)((xs4-(float)h4)*2048.0f); \
        _Float16 h5=(_Float16)xs5; hh_[5]=h5; ll_[5]=(_Float16)((xs5-(float)h5)*2048.0f); \
        _Float16 h6=(_Float16)xs6; hh_[6]=h6; ll_[6]=(_Float16)((xs6-(float)h6)*2048.0f); \
        _Float16 h7=(_Float16)xs7; hh_[7]=h7; ll_[7]=(_Float16)((xs7-(float)h7)*2048.0f); \
        *(f16x8*)&sA[buf][0][aidx] = hh_;                                 \
        *(f16x8*)&sA[buf][1][aidx] = ll_;                                 \
    } while (0)

#define STEP(buf, ks)                                                     \
    do {                                                                  \
        size_t ofA_ = (((size_t)(ks) * NCT) + ct0 + 0) * 512 + lane * 8;  \
        size_t ofB_ = (((size_t)(ks) * NCT) + ct0 + 1) * 512 + lane * 8;  \
        f16x8 bh0 = *(const f16x8*)(Whp + ofA_);                          \
        f16x8 bl0 = *(const f16x8*)(Wlp + ofA_);                          \
        f16x8 bh1 = *(const f16x8*)(Whp + ofB_);                          \
        f16x8 bl1 = *(const f16x8*)(Wlp + ofB_);                          \
        int r0_ = wm * 64 + 0 * 16 + (lane & 15);                         \
        int r1_ = wm * 64 + 1 * 16 + (lane & 15);                         \
        int r2_ = wm * 64 + 2 * 16 + (lane & 15);                         \
        int r3_ = wm * 64 + 3 * 16 + (lane & 15);                         \
        int i0_ = r0_ * 32 + 8 * ((lane >> 4) ^ ((r0_ >> 1) & 3));        \
        int i1_ = r1_ * 32 + 8 * ((lane >> 4) ^ ((r1_ >> 1) & 3));        \
        int i2_ = r2_ * 32 + 8 * ((lane >> 4) ^ ((r2_ >> 1) & 3));        \
        int i3_ = r3_ * 32 + 8 * ((lane >> 4) ^ ((r3_ >> 1) & 3));        \
        f16x8 ah0 = *(const f16x8*)&sA[buf][0][i0_];                      \
        f16x8 al0 = *(const f16x8*)&sA[buf][1][i0_];                      \
        f16x8 ah1 = *(const f16x8*)&sA[buf][0][i1_];                      \
        f16x8 al1 = *(const f16x8*)&sA[buf][1][i1_];                      \
        f16x8 ah2 = *(const f16x8*)&sA[buf][0][i2_];                      \
        f16x8 al2 = *(const f16x8*)&sA[buf][1][i2_];                      \
        f16x8 ah3 = *(const f16x8*)&sA[buf][0][i3_];                      \
        f16x8 al3 = *(const f16x8*)&sA[buf][1][i3_];                      \
        accA[0][0] = __builtin_amdgcn_mfma_f32_16x16x32_f16(ah0, bh0, accA[0][0], 0, 0, 0); \
        accB[0][0] = __builtin_amdgcn_mfma_f32_16x16x32_f16(ah0, bl0, accB[0][0], 0, 0, 0); \
        accB[0][0] = __builtin_amdgcn_mfma_f32_16x16x32_f16(al0, bh0, accB[0][0], 0, 0, 0); \
        accA[0][1] = __builtin_amdgcn_mfma_f32_16x16x32_f16(ah0, bh1, accA[0][1], 0, 0, 0); \
        accB[0][1] = __builtin_amdgcn_mfma_f32_16x16x32_f16(ah0, bl1, accB[0][1], 0, 0, 0); \
        accB[0][1] = __builtin_amdgcn_mfma_f32_16x16x32_f16(al0, bh1, accB[0][1], 0, 0, 0); \
        accA[1][0] = __builtin_amdgcn_mfma_f32_16x16x32_f16(ah1, bh0, accA[1][0], 0, 0, 0); \
        accB[1][0] = __builtin_amdgcn_mfma_f32_16x16x32_f16(ah1, bl0, accB[1][0], 0, 0, 0); \
        accB[1][0] = __builtin_amdgcn_mfma_f32_16x16x32_f16(al1, bh0, accB[1][0], 0, 0, 0); \
        accA[1][1] = __builtin_amdgcn_mfma_f32_16x16x32_f16(ah1, bh1, accA[1][1], 0, 0, 0); \
        accB[1][1] = __builtin_amdgcn_mfma_f32_16x16x32_f16(ah1, bl1, accB[1][1], 0, 0, 0); \
        accB[1][1] = __builtin_amdgcn_mfma_f32_16x16x32_f16(al1, bh1, accB[1][1], 0, 0, 0); \
        accA[2][0] = __builtin_amdgcn_mfma_f32_16x16x32_f16(ah2, bh0, accA[2][0], 0, 0, 0); \
        accB[2][0] = __builtin_amdgcn_mfma_f32_16x16x32_f16(ah2, bl0, accB[2][0], 0, 0, 0); \
        accB[2][0] = __builtin_amdgcn_mfma_f32_16x16x32_f16(al2, bh0, accB[2][0], 0, 0, 0); \
        accA[2][1] = __builtin_amdgcn_mfma_f32_16x16x32_f16(ah2, bh1, accA[2][1], 0, 0, 0); \
        accB[2][1] = __builtin_amdgcn_mfma_f32_16x16x32_f16(ah2, bl1, accB[2][1], 0, 0, 0); \
        accB[2][1] = __builtin_amdgcn_mfma_f32_16x16x32_f16(al2, bh1, accB[2][1], 0, 0, 0); \
        accA[3][0] = __builtin_amdgcn_mfma_f32_16x16x32_f16(ah3, bh0, accA[3][0], 0, 0, 0); \
        accB[3][0] = __builtin_amdgcn_mfma_f32_16x16x32_f16(ah3, bl0, accB[3][0], 0, 0, 0); \
        accB[3][0] = __builtin_amdgcn_mfma_f32_16x16x32_f16(al3, bh0, accB[3][0], 0, 0, 0); \
        accA[3][1] = __builtin_amdgcn_mfma_f32_16x16x32_f16(ah3, bh1, accA[3][1], 0, 0, 0); \
        accB[3][1] = __builtin_amdgcn_mfma_f32_16x16x32_f16(ah3, bl1, accB[3][1], 0, 0, 0); \
        accB[3][1] = __builtin_amdgcn_mfma_f32_16x16x32_f16(al3, bh1, accB[3][1], 0, 0, 0); \
    } while (0)

__global__ __launch_bounds__(512, 3) void mfma_logits9(
    const float* __restrict__ X,
    const _Float16* __restrict__ Whp, const _Float16* __restrict__ Wlp,
    const float* __restrict__ bias, float* __restrict__ logits)
{
    __shared__ _Float16 sA[2][2][128 * 32];   // 32 KB

    const int t = threadIdx.x;                // 0..511
    const int lane = t & 63;
    const int w = t >> 6;
    const int wm = w >> 2, wn = w & 3;        // 2M x 4N; wave tile 64x32

    // XCD swizzle: 5 N-blocks of an M-panel adjacent (2560 % 8 == 0)
    const int p = blockIdx.x;
    const int o = (p & 7) * 320 + (p >> 3);
    const int mb = o / 5, nb = o - mb * 5;
    const int row0 = mb * 128, n0 = nb * 128;
    const int ct0 = (n0 >> 4) + wn * 2;

    // A staging: thread owns (row = t>>2, k-octet q = t&3) of the 128x32 panel
    const int ar = t >> 2, aq = t & 3;
    const int aidx = ar * 32 + 8 * (aq ^ ((ar >> 1) & 3));  // XOR-swizzled LDS pos
    const float* aga = X + (size_t)(row0 + ar) * DIN + 8 * aq;

    f32x4 accA[4][2], accB[4][2];
    const f32x4 zz = {0.f, 0.f, 0.f, 0.f};
    #pragma unroll
    for (int mt = 0; mt < 4; ++mt)
        #pragma unroll
        for (int nt = 0; nt < 2; ++nt) { accA[mt][nt] = zz; accB[mt][nt] = zz; }

    // ---- prologue: stage A(0); pend p0=A(1), p1=A(2) ----
    float4 c0 = ((const float4*)(aga))[0];
    float4 c1 = ((const float4*)(aga))[1];
    WRITE_A(0, c0, c1);
    float4 p0a = ((const float4*)(aga + 32))[0];
    float4 p0b = ((const float4*)(aga + 32))[1];
    float4 p1a = ((const float4*)(aga + 64))[0];
    float4 p1b = ((const float4*)(aga + 64))[1];
    asm volatile("s_waitcnt lgkmcnt(0)" ::: "memory");
    __builtin_amdgcn_s_barrier();

    #pragma unroll 1
    for (int it = 0; it < 8; ++it) {
        const int ksE = 2 * it;
        // ======== step E (ks = ksE, buf 0): write A(ksE+1) from p0 (load ~2 steps old) ========
        STEP(0, ksE);
        WRITE_A(1, p0a, p0b);
        p0a = p1a; p0b = p1b;
        if (ksE + 3 < NKT) {
            p1a = ((const float4*)(aga + (ksE + 3) * 32))[0];
            p1b = ((const float4*)(aga + (ksE + 3) * 32))[1];
        }
        asm volatile("s_waitcnt lgkmcnt(0)" ::: "memory");
        __builtin_amdgcn_s_barrier();
        // ======== step O (ks = ksE+1, buf 1) ========
        STEP(1, ksE + 1);
        if (it < 7) {
            WRITE_A(0, p0a, p0b);
            p0a = p1a; p0b = p1b;
            if (ksE + 4 < NKT) {
                p1a = ((const float4*)(aga + (ksE + 4) * 32))[0];
                p1b = ((const float4*)(aga + (ksE + 4) * 32))[1];
            }
            asm volatile("s_waitcnt lgkmcnt(0)" ::: "memory");
            __builtin_amdgcn_s_barrier();
        }
    }

    // combine chains + bias, store f32 logits (identical expression to r8/r9)
    #pragma unroll
    for (int nt = 0; nt < 2; ++nt) {
        int col = n0 + wn * 32 + nt * 16 + (lane & 15);
        float bv = bias[col];
        #pragma unroll
        for (int mt = 0; mt < 4; ++mt) {
            #pragma unroll
            for (int q = 0; q < 4; ++q) {
                int row = row0 + wm * 64 + mt * 16 + (lane >> 4) * 4 + q;
                logits[(size_t)row * GC + col] =
                    accA[mt][nt][q] + accB[mt][nt][q] * (1.0f / 2048.0f) + bv;
            }
        }
    }
}

// ---------- epilogue: ballot-argmax, unstabilized usage softmax (r7-proven) ----------
#define RTB 32
__global__ __launch_bounds__(256, 8) void epilogue(
    const float* __restrict__ logits, const int* __restrict__ vlen,
    const float* __restrict__ U, const float* __restrict__ CB,
    float* __restrict__ out, float* __restrict__ gacc)
{
    __shared__ float uacc[GC];
    const int t = threadIdx.x;
    const int lane = t & 63;
    const int wid = t >> 6;
    const int row0 = blockIdx.x * RTB;

    for (int i = t; i < GC; i += 256) uacc[i] = 0.0f;
    __syncthreads();

    const int vl = vlen[row0 >> 12];

    float ureg[10];
    #pragma unroll
    for (int j = 0; j < 10; ++j) ureg[j] = 0.0f;

    #pragma unroll
    for (int r = 0; r < 8; ++r) {
        const int row = row0 + wid * 8 + r;
        const bool valid = (row & (NS - 1)) < vl;

        float lg[10], zz[10];
        #pragma unroll
        for (int j = 0; j < 10; ++j)
            lg[j] = logits[(size_t)row * GC + lane + 64 * j];
        #pragma unroll
        for (int j = 0; j < 10; ++j) {
            float u = U[(size_t)row * GC + lane + 64 * j];
            zz[j] = lg[j] - logf(-logf(u + EPSV) + EPSV);   // precise: argmax-critical
        }

        #pragma unroll
        for (int g = 0; g < 2; ++g) {
            const int j0 = g * 5;

            float mv = zz[j0];
            #pragma unroll
            for (int j = j0 + 1; j < j0 + 5; ++j) mv = fmaxf(mv, zz[j]);
            #pragma unroll
            for (int d = 1; d < 64; d <<= 1) mv = fmaxf(mv, __shfl_xor(mv, d));

            int c = 0;
            #pragma unroll
            for (int jj = 4; jj >= 0; --jj) {
                unsigned long long b = __ballot(zz[j0 + jj] == mv);
                if (b) c = (__ffsll(b) - 1) + 64 * jj;
            }

            float pe[5], s2 = 0.0f;
            #pragma unroll
            for (int jj = 0; jj < 5; ++jj) {
                pe[jj] = __expf(lg[j0 + jj]);
                s2 += pe[jj];
            }
            #pragma unroll
            for (int d = 1; d < 64; d <<= 1) s2 += __shfl_xor(s2, d);
            if (valid) {
                const float inv = 1.0f / s2;
                #pragma unroll
                for (int jj = 0; jj < 5; ++jj) ureg[j0 + jj] += pe[jj] * inv;
            }

            const float2 cv = ((const float2*)(CB + ((size_t)g * NC + c) * DG))[lane];
            ((float2*)(out + (size_t)row * (NG * DG) + g * DG))[lane] = cv;
        }
    }

    #pragma unroll
    for (int j = 0; j < 10; ++j)
        atomicAdd(&uacc[lane + 64 * j], ureg[j]);

    __syncthreads();
    for (int i = t; i < GC; i += 256) atomicAdd(&gacc[i], uacc[i]);
}

__global__ void finalize_usage(const float* __restrict__ gacc,
                               const int* __restrict__ vlen,
                               float* __restrict__ usage_out)
{
    int total = 0;
    #pragma unroll
    for (int b = 0; b < NB; ++b) total += vlen[b];
    int o = threadIdx.x;
    if (o < GC) usage_out[o] = gacc[o] / (float)total;
}

// ---------- lowest fallback (round-4, f32 VALU, proven 928 us) ----------
#define RT 32
#define KC 8
#define NIT (DIN/KC)

__global__ void transpose_w(const float* __restrict__ W, float* __restrict__ Wt) {
    int idx = blockIdx.x * 256 + threadIdx.x;
    if (idx >= GC * DIN) return;
    int k = idx / GC, o = idx - k * GC;
    Wt[idx] = W[(size_t)o * DIN + k];
}

__global__ __launch_bounds__(256, 2) void fused_main(
    const float* __restrict__ X, const int* __restrict__ vlen,
    const float* __restrict__ U, const float* __restrict__ Wt,
    const float* __restrict__ bias, const float* __restrict__ CB,
    const float* __restrict__ tptr, float* __restrict__ out,
    float* __restrict__ gacc)
{
    __shared__ __align__(16) float WtC[2][KC][GC];
    __shared__ __align__(16) float AC[2][RT][KC];
    __shared__ float uacc[GC];

    const int t = threadIdx.x;
    const int lane = t & 63;
    const int wid = t >> 6;
    const int row0 = blockIdx.x * RT;

    for (int i = t; i < GC; i += 256) uacc[i] = 0.0f;

    float acc[8][10];
    #pragma unroll
    for (int r = 0; r < 8; ++r)
        #pragma unroll
        for (int j = 0; j < 10; ++j) acc[r][j] = 0.0f;

    auto stage = [&](int b, int k0) {
        const float* gw = Wt + (size_t)k0 * GC;
        #pragma unroll
        for (int i = 0; i < 5; ++i) {
            int base = (wid * 5 + i) * 256;
            gload_lds16(gw + base + 4 * lane, &WtC[b][0][0] + base);
        }
        if (wid == 0) {
            const float* gx = X + (size_t)(row0 + (lane >> 1)) * DIN + k0 + 4 * (lane & 1);
            gload_lds16(gx, &AC[b][0][0]);
        }
    };

    stage(0, 0);
    __syncthreads();

    int cur = 0;
    for (int it = 0; it < NIT; ++it) {
        if (it + 1 < NIT) stage(cur ^ 1, (it + 1) * KC);
        #pragma unroll
        for (int kk = 0; kk < KC; ++kk) {
            float wv[10];
            #pragma unroll
            for (int j = 0; j < 10; ++j) wv[j] = WtC[cur][kk][lane + 64 * j];
            #pragma unroll
            for (int r = 0; r < 8; ++r) {
                float a = AC[cur][wid * 8 + r][kk];
                #pragma unroll
                for (int j = 0; j < 10; ++j) acc[r][j] = fmaf(a, wv[j], acc[r][j]);
            }
        }
        __syncthreads();
        cur ^= 1;
    }

    float bv[10];
    #pragma unroll
    for (int j = 0; j < 10; ++j) bv[j] = bias[lane + 64 * j];
    #pragma unroll
    for (int r = 0; r < 8; ++r)
        #pragma unroll
        for (int j = 0; j < 10; ++j) acc[r][j] += bv[j];

    const float T = *tptr;
    const int vl = vlen[row0 >> 12];

    #pragma unroll
    for (int r = 0; r < 8; ++r) {
        const int row = row0 + wid * 8 + r;
        const int ss = row & (NS - 1);
        const bool valid = ss < vl;

        float z[10];
        #pragma unroll
        for (int j = 0; j < 10; ++j) {
            float u = U[(size_t)row * GC + lane + 64 * j];
            float gn = -logf(-logf(u + EPSV) + EPSV);
            z[j] = (acc[r][j] + gn) / T;
        }

        #pragma unroll
        for (int g = 0; g < 2; ++g) {
            const int j0 = g * 5;
            float mv = z[j0];
            int mo = lane + 64 * j0;
            #pragma unroll
            for (int j = j0 + 1; j < j0 + 5; ++j) {
                if (z[j] > mv) { mv = z[j]; mo = lane + 64 * j; }
            }
            #pragma unroll
            for (int d = 1; d < 64; d <<= 1) {
                float ov = __shfl_xor(mv, d);
                int   oo = __shfl_xor(mo, d);
                if (ov > mv || (ov == mv && oo < mo)) { mv = ov; mo = oo; }
            }
            float se = 0.0f;
            #pragma unroll
            for (int j = j0; j < j0 + 5; ++j) se += expf(z[j] - mv);
            #pragma unroll
            for (int d = 1; d < 64; d <<= 1) se += __shfl_xor(se, d);
            float y = 1.0f / se;
            float q = (1.0f - y) + y;

            float m2 = acc[r][j0];
            #pragma unroll
            for (int j = j0 + 1; j < j0 + 5; ++j) m2 = fmaxf(m2, acc[r][j]);
            #pragma unroll
            for (int d = 1; d < 64; d <<= 1) m2 = fmaxf(m2, __shfl_xor(m2, d));
            float pe[5];
            float s2 = 0.0f;
            #pragma unroll
            for (int jj = 0; jj < 5; ++jj) {
                pe[jj] = expf(acc[r][j0 + jj] - m2);
                s2 += pe[jj];
            }
            #pragma unroll
            for (int d = 1; d < 64; d <<= 1) s2 += __shfl_xor(s2, d);
            if (valid) {
                #pragma unroll
                for (int jj = 0; jj < 5; ++jj)
                    atomicAdd(&uacc[lane + 64 * (j0 + jj)], pe[jj] / s2);
            }

            const int c = mo - g * NC;
            const float2 cv = ((const float2*)(CB + ((size_t)g * NC + c) * DG))[lane];
            float2 ov2;
            ov2.x = q * cv.x;
            ov2.y = q * cv.y;
            ((float2*)(out + (size_t)row * (NG * DG) + g * DG))[lane] = ov2;
        }
    }

    __syncthreads();
    for (int i = t; i < GC; i += 256) atomicAdd(&gacc[i], uacc[i]);
}

extern "C" void kernel_launch(void* const* d_in, const int* in_sizes, int n_in,
                              void* d_out, int out_size, void* d_ws, size_t ws_size,
                              hipStream_t stream)
{
    const float* X    = (const float*)d_in[0];
    const int*   vlen = (const int*)d_in[1];
    const float* U    = (const float*)d_in[2];
    const float* W    = (const float*)d_in[3];
    const float* bias = (const float*)d_in[4];
    const float* CB   = (const float*)d_in[5];
    const float* T    = (const float*)d_in[6];
    float* out = (float*)d_out;

    char* ws = (char*)d_ws;
    float*     gacc = (float*)ws;                               // 2,560
    _Float16*  Whp  = (_Float16*)(ws + 4096);                   // 655,360
    _Float16*  Wlp  = (_Float16*)(ws + 659456);                 // 655,360
    float*     lgts = (float*)(ws + 1314816);                   // 167,772,160
    float*     Wt   = (float*)(ws + 4096);                      // fallback only
    const size_t need = 1314816ull + 167772160ull;              // ~169 MB

    hipMemsetAsync(gacc, 0, GC * sizeof(float), stream);

    if (ws_size >= need) {
        cvt_split_pack<<<(GC * (DIN / 8) + 255) / 256, 256, 0, stream>>>(W, Whp, Wlp);
        mfma_logits9<<<(NROW / 128) * 5, 512, 0, stream>>>(X, Whp, Wlp, bias, lgts);
        epilogue<<<NROW / RTB, 256, 0, stream>>>(lgts, vlen, U, CB, out, gacc);
    } else {
        transpose_w<<<(GC * DIN + 255) / 256, 256, 0, stream>>>(W, Wt);
        fused_main<<<NROW / RT, 256, 0, stream>>>(X, vlen, U, Wt, bias, CB, T, out, gacc);
    }
    finalize_usage<<<1, GC, 0, stream>>>(gacc, vlen, out + (size_t)NROW * (NG * DG));
}

// Round 16
// 266.830 us; speedup vs baseline: 1.1861x; 1.1861x over previous
//
#include <hip/hip_runtime.h>
#include <math.h>

#define NB 16
#define NS 4096
#define DIN 512
#define NG 2
#define NC 320
#define GC 640          // NG*NC
#define DG 128          // D_out / G
#define NROW (NB*NS)    // 65536
#define EPSV 1e-10f

typedef __attribute__((ext_vector_type(4))) float f32x4;
typedef __attribute__((ext_vector_type(8))) _Float16 f16x8;
typedef __attribute__((ext_vector_type(4))) _Float16 f16x4v;

// async global->LDS, 16B per lane; lds dest is wave-uniform base (+ lane*16 by HW)
__device__ __forceinline__ void gload_lds16(const void* g, void* l) {
    __builtin_amdgcn_global_load_lds(
        (const __attribute__((address_space(1))) void*)g,
        (__attribute__((address_space(3))) void*)l,
        16, 0, 0);
}

// ---------- split f32 -> (f16 hi, f16 lo*2048)  (W only); also zeroes gacc ----------
__global__ __launch_bounds__(256) void cvt_split(
    const float* __restrict__ src, _Float16* __restrict__ h,
    _Float16* __restrict__ l, float* __restrict__ gacc, int n4)
{
    int i = blockIdx.x * 256 + threadIdx.x;
    if (i < GC) gacc[i] = 0.0f;                 // consumed only by later dispatches
    if (i >= n4) return;
    float4 v = ((const float4*)src)[i];
    f16x4v vh, vl;
    float xs[4] = {v.x, v.y, v.z, v.w};
    #pragma unroll
    for (int j = 0; j < 4; ++j) {
        _Float16 hh = (_Float16)xs[j];
        vh[j] = hh;
        vl[j] = (_Float16)((xs[j] - (float)hh) * 2048.0f);
    }
    ((f16x4v*)h)[i] = vh;
    ((f16x4v*)l)[i] = vl;
}

// ---------- MFMA GEMM (r8-proven, 187.8 us): 512 threads, inline X split ----------
// logits = Ah*Bh + 2^-11*(Ah*Bl + Al*Bh) + b
__global__ __launch_bounds__(512, 3) void mfma_logits2(
    const float* __restrict__ X,
    const _Float16* __restrict__ Wh, const _Float16* __restrict__ Wl,
    const float* __restrict__ bias, float* __restrict__ logits)
{
    __shared__ _Float16 sA[2][2][128 * 32];   // [buf][h/l], 32 KB
    __shared__ _Float16 sB[2][2][128 * 32];   // 32 KB

    const int t = threadIdx.x;                // 0..511
    const int lane = t & 63;
    const int w = t >> 6;                     // 0..7
    const int wm = w >> 2, wn = w & 3;        // 2M x 4N; per-wave 64x32 (4Mt x 2Nt)

    // grid remap: consecutive nb of one M-panel land on the same XCD
    const int p = blockIdx.x;
    const int o = (p & 7) * 320 + (p >> 3);
    const int mb = o / 5, nb = o - mb * 5;
    const int row0 = mb * 128, n0 = nb * 128;

    // B staging geometry (gload_lds, pre-swizzled source slot)
    const int rl = lane >> 2;                       // row within 16-row chunk
    const int sl = (lane & 3) ^ ((lane >> 3) & 3);  // source k-slot (XOR swizzle)

    auto stageB = [&](int b, int k0) {
        int ro = 16 * w + rl;                       // wave w covers rows 16w..16w+15
        size_t gb = (size_t)(n0 + ro) * DIN + k0 + 8 * sl;
        gload_lds16(Wh + gb, &sB[b][0][w * 512]);
        gload_lds16(Wl + gb, &sB[b][1][w * 512]);
    };

    // A reg-staging: thread t owns (row = t>>2, k-slot q = t&3) of the 128x32 panel
    const int ar = t >> 2, aq = t & 3;
    const int aidx = ar * 32 + 8 * (aq ^ ((ar >> 1) & 3));  // swizzled LDS pos
    const float* aga = X + (size_t)(row0 + ar) * DIN + 8 * aq;

    float4 a0, a1;
    auto loadA = [&](int k0) {
        a0 = ((const float4*)(aga + k0))[0];
        a1 = ((const float4*)(aga + k0))[1];
    };
    auto writeA = [&](int b) {
        float xs[8] = {a0.x, a0.y, a0.z, a0.w, a1.x, a1.y, a1.z, a1.w};
        f16x8 h, l;
        #pragma unroll
        for (int j = 0; j < 8; ++j) {
            _Float16 hh = (_Float16)xs[j];
            h[j] = hh;
            l[j] = (_Float16)((xs[j] - (float)hh) * 2048.0f);
        }
        *(f16x8*)&sA[b][0][aidx] = h;
        *(f16x8*)&sA[b][1][aidx] = l;
    };

    f32x4 accA[4][2], accB[4][2];
    const f32x4 zz = {0.f, 0.f, 0.f, 0.f};
    #pragma unroll
    for (int mt = 0; mt < 4; ++mt)
        #pragma unroll
        for (int nt = 0; nt < 2; ++nt) { accA[mt][nt] = zz; accB[mt][nt] = zz; }

    loadA(0);
    stageB(0, 0);
    writeA(0);
    __syncthreads();

    for (int ks = 0; ks < 16; ++ks) {
        const int cur = ks & 1;
        if (ks < 15) { loadA((ks + 1) * 32); stageB(cur ^ 1, (ks + 1) * 32); }

        f16x8 ah[4], al[4], bh[2], bl[2];
        #pragma unroll
        for (int mt = 0; mt < 4; ++mt) {
            int r = wm * 64 + mt * 16 + (lane & 15);
            int idx = r * 32 + 8 * ((lane >> 4) ^ ((r >> 1) & 3));
            ah[mt] = *(const f16x8*)&sA[cur][0][idx];
            al[mt] = *(const f16x8*)&sA[cur][1][idx];
        }
        #pragma unroll
        for (int nt = 0; nt < 2; ++nt) {
            int r = wn * 32 + nt * 16 + (lane & 15);
            int idx = r * 32 + 8 * ((lane >> 4) ^ ((r >> 1) & 3));
            bh[nt] = *(const f16x8*)&sB[cur][0][idx];
            bl[nt] = *(const f16x8*)&sB[cur][1][idx];
        }
        #pragma unroll
        for (int mt = 0; mt < 4; ++mt)
            #pragma unroll
            for (int nt = 0; nt < 2; ++nt) {
                accA[mt][nt] = __builtin_amdgcn_mfma_f32_16x16x32_f16(ah[mt], bh[nt], accA[mt][nt], 0, 0, 0);
                accB[mt][nt] = __builtin_amdgcn_mfma_f32_16x16x32_f16(ah[mt], bl[nt], accB[mt][nt], 0, 0, 0);
                accB[mt][nt] = __builtin_amdgcn_mfma_f32_16x16x32_f16(al[mt], bh[nt], accB[mt][nt], 0, 0, 0);
            }

        if (ks < 15) writeA(cur ^ 1);   // vmcnt wait lands after compute
        __syncthreads();
    }

    // combine chains + bias, store f32 logits
    #pragma unroll
    for (int nt = 0; nt < 2; ++nt) {
        int col = n0 + wn * 32 + nt * 16 + (lane & 15);
        float bv = bias[col];
        #pragma unroll
        for (int mt = 0; mt < 4; ++mt) {
            #pragma unroll
            for (int q = 0; q < 4; ++q) {
                int row = row0 + wm * 64 + mt * 16 + (lane >> 4) * 4 + q;
                logits[(size_t)row * GC + col] =
                    accA[mt][nt][q] + accB[mt][nt][q] * (1.0f / 2048.0f) + bv;
            }
        }
    }
}

// ---------- epilogue: ballot-argmax, unstabilized usage softmax (r7-proven) ----------
#define RTB 32
__global__ __launch_bounds__(256, 8) void epilogue(
    const float* __restrict__ logits, const int* __restrict__ vlen,
    const float* __restrict__ U, const float* __restrict__ CB,
    float* __restrict__ out, float* __restrict__ gacc)
{
    __shared__ float uacc[GC];
    const int t = threadIdx.x;
    const int lane = t & 63;
    const int wid = t >> 6;
    const int row0 = blockIdx.x * RTB;

    for (int i = t; i < GC; i += 256) uacc[i] = 0.0f;
    __syncthreads();

    const int vl = vlen[row0 >> 12];

    float ureg[10];
    #pragma unroll
    for (int j = 0; j < 10; ++j) ureg[j] = 0.0f;

    #pragma unroll
    for (int r = 0; r < 8; ++r) {
        const int row = row0 + wid * 8 + r;
        const bool valid = (row & (NS - 1)) < vl;

        float lg[10], zz[10];
        #pragma unroll
        for (int j = 0; j < 10; ++j)
            lg[j] = logits[(size_t)row * GC + lane + 64 * j];
        #pragma unroll
        for (int j = 0; j < 10; ++j) {
            float u = U[(size_t)row * GC + lane + 64 * j];
            zz[j] = lg[j] - logf(-logf(u + EPSV) + EPSV);   // precise: argmax-critical
        }

        #pragma unroll
        for (int g = 0; g < 2; ++g) {
            const int j0 = g * 5;

            float mv = zz[j0];
            #pragma unroll
            for (int j = j0 + 1; j < j0 + 5; ++j) mv = fmaxf(mv, zz[j]);
            #pragma unroll
            for (int d = 1; d < 64; d <<= 1) mv = fmaxf(mv, __shfl_xor(mv, d));

            int c = 0;
            #pragma unroll
            for (int jj = 4; jj >= 0; --jj) {
                unsigned long long b = __ballot(zz[j0 + jj] == mv);
                if (b) c = (__ffsll(b) - 1) + 64 * jj;
            }

            float pe[5], s2 = 0.0f;
            #pragma unroll
            for (int jj = 0; jj < 5; ++jj) {
                pe[jj] = __expf(lg[j0 + jj]);
                s2 += pe[jj];
            }
            #pragma unroll
            for (int d = 1; d < 64; d <<= 1) s2 += __shfl_xor(s2, d);
            if (valid) {
                const float inv = 1.0f / s2;
                #pragma unroll
                for (int jj = 0; jj < 5; ++jj) ureg[j0 + jj] += pe[jj] * inv;
            }

            const float2 cv = ((const float2*)(CB + ((size_t)g * NC + c) * DG))[lane];
            ((float2*)(out + (size_t)row * (NG * DG) + g * DG))[lane] = cv;
        }
    }

    #pragma unroll
    for (int j = 0; j < 10; ++j)
        atomicAdd(&uacc[lane + 64 * j], ureg[j]);

    __syncthreads();
    for (int i = t; i < GC; i += 256) atomicAdd(&gacc[i], uacc[i]);
}

__global__ void finalize_usage(const float* __restrict__ gacc,
                               const int* __restrict__ vlen,
                               float* __restrict__ usage_out)
{
    int total = 0;
    #pragma unroll
    for (int b = 0; b < NB; ++b) total += vlen[b];
    int o = threadIdx.x;
    if (o < GC) usage_out[o] = gacc[o] / (float)total;
}

// ---------- fallback path (round-4, f32 VALU, proven 928 us) ----------
#define RT 32
#define KC 8
#define NIT (DIN/KC)

__global__ void transpose_w(const float* __restrict__ W, float* __restrict__ Wt) {
    int idx = blockIdx.x * 256 + threadIdx.x;
    if (idx >= GC * DIN) return;
    int k = idx / GC, o = idx - k * GC;
    Wt[idx] = W[(size_t)o * DIN + k];
}

__global__ __launch_bounds__(256, 2) void fused_main(
    const float* __restrict__ X, const int* __restrict__ vlen,
    const float* __restrict__ U, const float* __restrict__ Wt,
    const float* __restrict__ bias, const float* __restrict__ CB,
    const float* __restrict__ tptr, float* __restrict__ out,
    float* __restrict__ gacc)
{
    __shared__ __align__(16) float WtC[2][KC][GC];
    __shared__ __align__(16) float AC[2][RT][KC];
    __shared__ float uacc[GC];

    const int t = threadIdx.x;
    const int lane = t & 63;
    const int wid = t >> 6;
    const int row0 = blockIdx.x * RT;

    for (int i = t; i < GC; i += 256) uacc[i] = 0.0f;

    float acc[8][10];
    #pragma unroll
    for (int r = 0; r < 8; ++r)
        #pragma unroll
        for (int j = 0; j < 10; ++j) acc[r][j] = 0.0f;

    auto stage = [&](int b, int k0) {
        const float* gw = Wt + (size_t)k0 * GC;
        #pragma unroll
        for (int i = 0; i < 5; ++i) {
            int base = (wid * 5 + i) * 256;
            gload_lds16(gw + base + 4 * lane, &WtC[b][0][0] + base);
        }
        if (wid == 0) {
            const float* gx = X + (size_t)(row0 + (lane >> 1)) * DIN + k0 + 4 * (lane & 1);
            gload_lds16(gx, &AC[b][0][0]);
        }
    };

    stage(0, 0);
    __syncthreads();

    int cur = 0;
    for (int it = 0; it < NIT; ++it) {
        if (it + 1 < NIT) stage(cur ^ 1, (it + 1) * KC);
        #pragma unroll
        for (int kk = 0; kk < KC; ++kk) {
            float wv[10];
            #pragma unroll
            for (int j = 0; j < 10; ++j) wv[j] = WtC[cur][kk][lane + 64 * j];
            #pragma unroll
            for (int r = 0; r < 8; ++r) {
                float a = AC[cur][wid * 8 + r][kk];
                #pragma unroll
                for (int j = 0; j < 10; ++j) acc[r][j] = fmaf(a, wv[j], acc[r][j]);
            }
        }
        __syncthreads();
        cur ^= 1;
    }

    float bv[10];
    #pragma unroll
    for (int j = 0; j < 10; ++j) bv[j] = bias[lane + 64 * j];
    #pragma unroll
    for (int r = 0; r < 8; ++r)
        #pragma unroll
        for (int j = 0; j < 10; ++j) acc[r][j] += bv[j];

    const float T = *tptr;
    const int vl = vlen[row0 >> 12];

    #pragma unroll
    for (int r = 0; r < 8; ++r) {
        const int row = row0 + wid * 8 + r;
        const int ss = row & (NS - 1);
        const bool valid = ss < vl;

        float z[10];
        #pragma unroll
        for (int j = 0; j < 10; ++j) {
            float u = U[(size_t)row * GC + lane + 64 * j];
            float gn = -logf(-logf(u + EPSV) + EPSV);
            z[j] = (acc[r][j] + gn) / T;
        }

        #pragma unroll
        for (int g = 0; g < 2; ++g) {
            const int j0 = g * 5;
            float mv = z[j0];
            int mo = lane + 64 * j0;
            #pragma unroll
            for (int j = j0 + 1; j < j0 + 5; ++j) {
                if (z[j] > mv) { mv = z[j]; mo = lane + 64 * j; }
            }
            #pragma unroll
            for (int d = 1; d < 64; d <<= 1) {
                float ov = __shfl_xor(mv, d);
                int   oo = __shfl_xor(mo, d);
                if (ov > mv || (ov == mv && oo < mo)) { mv = ov; mo = oo; }
            }
            float se = 0.0f;
            #pragma unroll
            for (int j = j0; j < j0 + 5; ++j) se += expf(z[j] - mv);
            #pragma unroll
            for (int d = 1; d < 64; d <<= 1) se += __shfl_xor(se, d);
            float y = 1.0f / se;
            float q = (1.0f - y) + y;

            float m2 = acc[r][j0];
            #pragma unroll
            for (int j = j0 + 1; j < j0 + 5; ++j) m2 = fmaxf(m2, acc[r][j]);
            #pragma unroll
            for (int d = 1; d < 64; d <<= 1) m2 = fmaxf(m2, __shfl_xor(m2, d));
            float pe[5];
            float s2 = 0.0f;
            #pragma unroll
            for (int jj = 0; jj < 5; ++jj) {
                pe[jj] = expf(acc[r][j0 + jj] - m2);
                s2 += pe[jj];
            }
            #pragma unroll
            for (int d = 1; d < 64; d <<= 1) s2 += __shfl_xor(s2, d);
            if (valid) {
                #pragma unroll
                for (int jj = 0; jj < 5; ++jj)
                    atomicAdd(&uacc[lane + 64 * (j0 + jj)], pe[jj] / s2);
            }

            const int c = mo - g * NC;
            const float2 cv = ((const float2*)(CB + ((size_t)g * NC + c) * DG))[lane];
            float2 ov2;
            ov2.x = q * cv.x;
            ov2.y = q * cv.y;
            ((float2*)(out + (size_t)row * (NG * DG) + g * DG))[lane] = ov2;
        }
    }

    __syncthreads();
    for (int i = t; i < GC; i += 256) atomicAdd(&gacc[i], uacc[i]);
}

extern "C" void kernel_launch(void* const* d_in, const int* in_sizes, int n_in,
                              void* d_out, int out_size, void* d_ws, size_t ws_size,
                              hipStream_t stream)
{
    const float* X    = (const float*)d_in[0];
    const int*   vlen = (const int*)d_in[1];
    const float* U    = (const float*)d_in[2];
    const float* W    = (const float*)d_in[3];
    const float* bias = (const float*)d_in[4];
    const float* CB   = (const float*)d_in[5];
    const float* T    = (const float*)d_in[6];
    float* out = (float*)d_out;

    char* ws = (char*)d_ws;
    float*     gacc = (float*)ws;                               // 2,560
    _Float16*  Whh  = (_Float16*)(ws + 4096);                   // 655,360
    _Float16*  Wll  = (_Float16*)(ws + 659456);                 // 655,360
    float*     lgts = (float*)(ws + 1314816);                   // 167,772,160
    float*     Wt   = (float*)(ws + 4096);                      // fallback only
    const size_t need = 1314816ull + 167772160ull;              // ~169 MB

    if (ws_size >= need) {
        const int nw4 = GC * DIN / 4;     // 81,920
        cvt_split<<<(nw4 + 255) / 256, 256, 0, stream>>>(W, Whh, Wll, gacc, nw4);
        mfma_logits2<<<(NROW / 128) * 5, 512, 0, stream>>>(X, Whh, Wll, bias, lgts);
        epilogue<<<NROW / RTB, 256, 0, stream>>>(lgts, vlen, U, CB, out, gacc);
    } else {
        hipMemsetAsync(gacc, 0, GC * sizeof(float), stream);
        transpose_w<<<(GC * DIN + 255) / 256, 256, 0, stream>>>(W, Wt);
        fused_main<<<NROW / RT, 256, 0, stream>>>(X, vlen, U, Wt, bias, CB, T, out, gacc);
    }
    finalize_usage<<<1, GC, 0, stream>>>(gacc, vlen, out + (size_t)NROW * (NG * DG));
}